// Round 3
// baseline (30.861 us; speedup 1.0000x reference)
//
#include <hip/hip_runtime.h>
#include <math.h>

#define QTE_D      768
#define QTE_Q      10
#define QTE_DPL    12     // gates per lane (768 / 64)
#define QTE_NSTATE 1024   // 2^10
#define QTE_BLK    256    // 4 waves per block
#define QTE_NWAVE  4

struct qte_c32 { float x, y; };

__device__ __forceinline__ qte_c32 qte_cmul(qte_c32 a, qte_c32 b) {
    qte_c32 r;
    r.x = fmaf(a.x, b.x, -(a.y * b.y));
    r.y = fmaf(a.x, b.y,   a.y * b.x);
    return r;
}

// acc + a*b
__device__ __forceinline__ qte_c32 qte_cfma(qte_c32 a, qte_c32 b, qte_c32 acc) {
    acc.x = fmaf(a.x, b.x, fmaf(-a.y, b.y, acc.x));
    acc.y = fmaf(a.x, b.y, fmaf( a.y, b.x, acc.y));
    return acc;
}

__device__ __forceinline__ qte_c32 qte_shflx(qte_c32 v, int mask) {
    qte_c32 r;
    r.x = __shfl_xor(v.x, mask);
    r.y = __shfl_xor(v.y, mask);
    return r;
}

__global__ __launch_bounds__(QTE_BLK)
void qte_kernel(const float* __restrict__ emb,
                const float* __restrict__ prm,
                float* __restrict__ out,
                int out_floats) {
    __shared__ float  s_scaled[QTE_D];
    __shared__ float2 s_v[QTE_Q][2];

    const int bs  = blockIdx.x;
    const int tid = threadIdx.x;
    const int wv  = tid >> 6;
    const int ln  = tid & 63;

    // Stage tanh(emb)*pi once per (b,s)
    for (int d = tid; d < QTE_D; d += QTE_BLK) {
        s_scaled[d] = tanhf(emb[bs * QTE_D + d]) * 3.14159265358979323846f;
    }
    __syncthreads();

    // Each wave handles q = wv, wv+4, wv+8 (q < 10)
    for (int q = wv; q < QTE_Q; q += QTE_NWAVE) {
        // Lane ln: ordered product of gates d = ln*12 .. ln*12+11
        qte_c32 m00 = {1.f, 0.f}, m01 = {0.f, 0.f};
        qte_c32 m10 = {0.f, 0.f}, m11 = {1.f, 0.f};
        const int dbase = ln * QTE_DPL;

        for (int k = 0; k < QTE_DPL; ++k) {
            const int d = dbase + k;
            const float t = 0.5f * s_scaled[d];
            const float* p = &prm[(d * QTE_Q + q) * 3];
            const float a0 = t * p[0];
            const float a1 = t * p[1];
            const float a2 = t * p[2];
            float s0, c0, s1, c1, s2, c2;
            sincosf(a0, &s0, &c0);
            sincosf(a1, &s1, &c1);
            sincosf(a2, &s2, &c2);

            const qte_c32 ph  = { c2, -s2 };   // exp(-i a2)
            const qte_c32 phc = { c2,  s2 };   // conj(ph)
            const qte_c32 t00 = {  c1 * c0,  s1 * s0 };
            const qte_c32 t01 = { -s1 * c0, -c1 * s0 };
            const qte_c32 t10 = {  s1 * c0, -c1 * s0 };
            const qte_c32 t11 = {  c1 * c0, -s1 * s0 };
            const qte_c32 g00 = qte_cmul(ph,  t00);
            const qte_c32 g01 = qte_cmul(ph,  t01);
            const qte_c32 g10 = qte_cmul(phc, t10);
            const qte_c32 g11 = qte_cmul(phc, t11);

            // M = G * M
            const qte_c32 n00 = qte_cfma(g00, m00, qte_cmul(g01, m10));
            const qte_c32 n01 = qte_cfma(g00, m01, qte_cmul(g01, m11));
            const qte_c32 n10 = qte_cfma(g10, m00, qte_cmul(g11, m10));
            const qte_c32 n11 = qte_cfma(g10, m01, qte_cmul(g11, m11));
            m00 = n00; m01 = n01; m10 = n10; m11 = n11;
        }

        // Butterfly combine across the wave; higher-d partial multiplies LEFT.
        for (int mask = 1; mask < 64; mask <<= 1) {
            const qte_c32 p00 = qte_shflx(m00, mask);
            const qte_c32 p01 = qte_shflx(m01, mask);
            const qte_c32 p10 = qte_shflx(m10, mask);
            const qte_c32 p11 = qte_shflx(m11, mask);
            const bool lower = (ln & mask) == 0;
            const qte_c32 A00 = lower ? p00 : m00, A01 = lower ? p01 : m01;
            const qte_c32 A10 = lower ? p10 : m10, A11 = lower ? p11 : m11;
            const qte_c32 B00 = lower ? m00 : p00, B01 = lower ? m01 : p01;
            const qte_c32 B10 = lower ? m10 : p10, B11 = lower ? m11 : p11;
            m00 = qte_cfma(A00, B00, qte_cmul(A01, B10));
            m01 = qte_cfma(A00, B01, qte_cmul(A01, B11));
            m10 = qte_cfma(A10, B00, qte_cmul(A11, B10));
            m11 = qte_cfma(A10, B01, qte_cmul(A11, B11));
        }

        // v = M . [1,0]^T (column 0)
        if (ln == 0) {
            s_v[q][0] = make_float2(m00.x, m00.y);
            s_v[q][1] = make_float2(m10.x, m10.y);
        }
    }
    __syncthreads();

    // Kronecker product: state[i] = prod_q v[q][bit_q], q=0 most significant.
    // Harness compares the REAL PART only (out_size = B*S*1024 float32).
    for (int i = tid; i < QTE_NSTATE; i += QTE_BLK) {
        float2 a = s_v[0][(i >> (QTE_Q - 1)) & 1];
        qte_c32 acc = { a.x, a.y };
        for (int q = 1; q < QTE_Q; ++q) {
            const float2 b = s_v[q][(i >> (QTE_Q - 1 - q)) & 1];
            const qte_c32 cb = { b.x, b.y };
            acc = qte_cmul(acc, cb);
        }
        const int idx = bs * QTE_NSTATE + i;
        if (idx < out_floats) {
            out[idx] = acc.x;   // real part only
        }
    }
}

extern "C" void kernel_launch(void* const* d_in, const int* in_sizes, int n_in,
                              void* d_out, int out_size, void* d_ws, size_t ws_size,
                              hipStream_t stream) {
    const float* emb = (const float*)d_in[0];  // [B,S,D] float32
    const float* prm = (const float*)d_in[1];  // [D,Q,3] float32
    float* out = (float*)d_out;                // [B,S,1024] float32 (real part of state)

    const int BS = in_sizes[0] / QTE_D;        // B*S = 512
    qte_kernel<<<BS, QTE_BLK, 0, stream>>>(emb, prm, out, out_size);
}

// Round 4
// 24.825 us; speedup vs baseline: 1.2432x; 1.2432x over previous
//
#include <hip/hip_runtime.h>
#include <math.h>

#define QTE_D       768
#define QTE_Q       10
#define QTE_DPL     12     // gates per lane (768 / 64)
#define QTE_NSTATE  1024   // 2^10
#define QTE_BLK     640    // 10 waves: one wave per qubit chain
#define QTE_FAST_TRIG 1

struct qte_c32 { float x, y; };

__device__ __forceinline__ qte_c32 qte_cmul(qte_c32 a, qte_c32 b) {
    qte_c32 r;
    r.x = fmaf(a.x, b.x, -(a.y * b.y));
    r.y = fmaf(a.x, b.y,   a.y * b.x);
    return r;
}

// acc + a*b
__device__ __forceinline__ qte_c32 qte_cfma(qte_c32 a, qte_c32 b, qte_c32 acc) {
    acc.x = fmaf(a.x, b.x, fmaf(-a.y, b.y, acc.x));
    acc.y = fmaf(a.x, b.y, fmaf( a.y, b.x, acc.y));
    return acc;
}

__device__ __forceinline__ qte_c32 qte_shflx(qte_c32 v, int mask) {
    qte_c32 r;
    r.x = __shfl_xor(v.x, mask);
    r.y = __shfl_xor(v.y, mask);
    return r;
}

__device__ __forceinline__ void qte_sincos(float a, float* s, float* c) {
#if QTE_FAST_TRIG
    *s = __sinf(a);
    *c = __cosf(a);
#else
    sincosf(a, s, c);
#endif
}

__global__ __launch_bounds__(QTE_BLK)
void qte_kernel(const float* __restrict__ emb,
                const float* __restrict__ prm,
                float* __restrict__ out,
                int out_floats) {
    __shared__ float  s_scaled[QTE_D];
    __shared__ float2 s_v[QTE_Q][2];

    const int bs  = blockIdx.x;
    const int tid = threadIdx.x;
    const int q   = tid >> 6;   // wave index == qubit index
    const int ln  = tid & 63;

    // Stage tanh(emb)*pi once per (b,s)
    for (int d = tid; d < QTE_D; d += QTE_BLK) {
        s_scaled[d] = tanhf(emb[bs * QTE_D + d]) * 3.14159265358979323846f;
    }
    __syncthreads();

    // --- one wave per q: lane ln owns gates d = ln*12 .. ln*12+11 ---
    qte_c32 m00 = {1.f, 0.f}, m01 = {0.f, 0.f};
    qte_c32 m10 = {0.f, 0.f}, m11 = {1.f, 0.f};
    const int dbase = ln * QTE_DPL;
    const float* pbase = &prm[(dbase * QTE_Q + q) * 3];

    for (int k = 0; k < QTE_DPL; ++k) {
        const float t = 0.5f * s_scaled[dbase + k];
        const float* p = pbase + k * (QTE_Q * 3);
        const float a0 = t * p[0];
        const float a1 = t * p[1];
        const float a2 = t * p[2];
        float s0, c0, s1, c1, s2, c2;
        qte_sincos(a0, &s0, &c0);
        qte_sincos(a1, &s1, &c1);
        qte_sincos(a2, &s2, &c2);

        const qte_c32 ph  = { c2, -s2 };   // exp(-i a2)
        const qte_c32 phc = { c2,  s2 };   // conj(ph)
        const qte_c32 t00 = {  c1 * c0,  s1 * s0 };
        const qte_c32 t01 = { -s1 * c0, -c1 * s0 };
        const qte_c32 t10 = {  s1 * c0, -c1 * s0 };
        const qte_c32 t11 = {  c1 * c0, -s1 * s0 };
        const qte_c32 g00 = qte_cmul(ph,  t00);
        const qte_c32 g01 = qte_cmul(ph,  t01);
        const qte_c32 g10 = qte_cmul(phc, t10);
        const qte_c32 g11 = qte_cmul(phc, t11);

        // M = G * M
        const qte_c32 n00 = qte_cfma(g00, m00, qte_cmul(g01, m10));
        const qte_c32 n01 = qte_cfma(g00, m01, qte_cmul(g01, m11));
        const qte_c32 n10 = qte_cfma(g10, m00, qte_cmul(g11, m10));
        const qte_c32 n11 = qte_cfma(g10, m01, qte_cmul(g11, m11));
        m00 = n00; m01 = n01; m10 = n10; m11 = n11;
    }

    // Butterfly combine across the wave; higher-d partial multiplies LEFT.
    for (int mask = 1; mask < 64; mask <<= 1) {
        const qte_c32 p00 = qte_shflx(m00, mask);
        const qte_c32 p01 = qte_shflx(m01, mask);
        const qte_c32 p10 = qte_shflx(m10, mask);
        const qte_c32 p11 = qte_shflx(m11, mask);
        const bool lower = (ln & mask) == 0;
        const qte_c32 A00 = lower ? p00 : m00, A01 = lower ? p01 : m01;
        const qte_c32 A10 = lower ? p10 : m10, A11 = lower ? p11 : m11;
        const qte_c32 B00 = lower ? m00 : p00, B01 = lower ? m01 : p01;
        const qte_c32 B10 = lower ? m10 : p10, B11 = lower ? m11 : p11;
        m00 = qte_cfma(A00, B00, qte_cmul(A01, B10));
        m01 = qte_cfma(A00, B01, qte_cmul(A01, B11));
        m10 = qte_cfma(A10, B00, qte_cmul(A11, B10));
        m11 = qte_cfma(A10, B01, qte_cmul(A11, B11));
    }

    // v = M . [1,0]^T (column 0)
    if (ln == 0) {
        s_v[q][0] = make_float2(m00.x, m00.y);
        s_v[q][1] = make_float2(m10.x, m10.y);
    }
    __syncthreads();

    // Kronecker product: state[i] = prod_q v[q][bit_q], q=0 most significant.
    // Harness compares the REAL PART only (out_size = B*S*1024 float32).
    for (int i = tid; i < QTE_NSTATE; i += QTE_BLK) {
        float2 a = s_v[0][(i >> (QTE_Q - 1)) & 1];
        qte_c32 acc = { a.x, a.y };
        for (int qq = 1; qq < QTE_Q; ++qq) {
            const float2 b = s_v[qq][(i >> (QTE_Q - 1 - qq)) & 1];
            const qte_c32 cb = { b.x, b.y };
            acc = qte_cmul(acc, cb);
        }
        const int idx = bs * QTE_NSTATE + i;
        if (idx < out_floats) {
            out[idx] = acc.x;   // real part only
        }
    }
}

extern "C" void kernel_launch(void* const* d_in, const int* in_sizes, int n_in,
                              void* d_out, int out_size, void* d_ws, size_t ws_size,
                              hipStream_t stream) {
    const float* emb = (const float*)d_in[0];  // [B,S,D] float32
    const float* prm = (const float*)d_in[1];  // [D,Q,3] float32
    float* out = (float*)d_out;                // [B,S,1024] float32 (real part of state)

    const int BS = in_sizes[0] / QTE_D;        // B*S = 512
    qte_kernel<<<BS, QTE_BLK, 0, stream>>>(emb, prm, out, out_size);
}

// Round 5
// 21.213 us; speedup vs baseline: 1.4548x; 1.1703x over previous
//
#include <hip/hip_runtime.h>
#include <math.h>

#define QTE_D      768
#define QTE_Q      10
#define QTE_DPL    12     // gates per lane (768 / 64)
#define QTE_NSTATE 1024   // 2^10
#define QTE_BLK    640    // 10 waves: one wave per qubit chain

struct qc { float x, y; };

// SU(2) matrix is [[A, B], [-conj(B), conj(A)]]; product P*M tracked as (A,B).
// oA = pA*mA - pB*conj(mB); oB = pA*mB + pB*conj(mA)
__device__ __forceinline__ void qte_su2mul(qc pA, qc pB, qc mA, qc mB,
                                           qc* oA, qc* oB) {
    oA->x = fmaf(pA.x, mA.x, fmaf(-pA.y, mA.y, fmaf(-pB.x, mB.x, -(pB.y * mB.y))));
    oA->y = fmaf(pA.x, mA.y, fmaf( pA.y, mA.x, fmaf( pB.x, mB.y, -(pB.y * mB.x))));
    oB->x = fmaf(pA.x, mB.x, fmaf(-pA.y, mB.y, fmaf( pB.x, mA.x,   pB.y * mA.y)));
    oB->y = fmaf(pA.x, mB.y, fmaf( pA.y, mB.x, fmaf(-pB.x, mA.y,   pB.y * mA.x)));
}

__device__ __forceinline__ float qte_tanh(float x) {
    const float e = __expf(2.0f * x);
    return (e - 1.0f) * __builtin_amdgcn_rcpf(e + 1.0f);
}

// Composite gate Rz(2a2)Ry(2a1)Rx(2a0) with a_j = tau*p_j; returns (a,b) of SU(2).
// a = ph*(c1c0 + i s1s0), b = ph*(-i c1s0 - s1c0), ph = exp(-i a2)
__device__ __forceinline__ void qte_gate(float tau, float p0, float p1, float p2,
                                         qc* a, qc* b) {
    const float a0 = tau * p0, a1 = tau * p1, a2 = tau * p2;
    const float s0 = __sinf(a0), c0 = __cosf(a0);
    const float s1 = __sinf(a1), c1 = __cosf(a1);
    const float s2 = __sinf(a2), c2 = __cosf(a2);
    const float u = c1 * c0, v = s1 * s0;
    const float w = s1 * c0, z = c1 * s0;
    a->x =  fmaf(c2, u,   s2 * v);
    a->y =  fmaf(c2, v, -(s2 * u));
    b->x = -fmaf(c2, w,   s2 * z);
    b->y =  fmaf(s2, w, -(c2 * z));
}

__global__ __launch_bounds__(QTE_BLK, 5)
void qte_kernel(const float* __restrict__ emb,
                const float* __restrict__ prm,
                float* __restrict__ out,
                int out_floats) {
    __shared__ float2 s_v[QTE_Q][2];

    const int bs  = blockIdx.x;
    const int tid = threadIdx.x;
    const int q   = tid >> 6;   // wave index == qubit index
    const int ln  = tid & 63;

    // Per-lane emb chunk: 12 contiguous floats, 16B-aligned -> 3x float4
    const float* eb = emb + bs * QTE_D + ln * QTE_DPL;
    const float4 e0 = *reinterpret_cast<const float4*>(eb);
    const float4 e1 = *reinterpret_cast<const float4*>(eb + 4);
    const float4 e2 = *reinterpret_cast<const float4*>(eb + 8);
    const float xs[QTE_DPL] = { e0.x, e0.y, e0.z, e0.w,
                                e1.x, e1.y, e1.z, e1.w,
                                e2.x, e2.y, e2.z, e2.w };
    float tau[QTE_DPL];
    #pragma unroll
    for (int j = 0; j < QTE_DPL; ++j) {
        tau[j] = 1.57079632679489662f * qte_tanh(xs[j]);  // (pi/2)*tanh
    }

    const float* pb = prm + (ln * QTE_DPL * QTE_Q + q) * 3;

    // Pair-tree chain: M = P5*P4*...*P0, P_k = G_{2k+1}*G_{2k}
    qc MA, MB;
    #pragma unroll
    for (int pr = 0; pr < QTE_DPL / 2; ++pr) {
        const int k0 = 2 * pr;
        const float* P0 = pb + k0 * (QTE_Q * 3);
        const float* P1 = P0 + QTE_Q * 3;
        qc a0, b0, a1, b1;
        qte_gate(tau[k0],     P0[0], P0[1], P0[2], &a0, &b0);
        qte_gate(tau[k0 + 1], P1[0], P1[1], P1[2], &a1, &b1);
        qc pA, pB;
        qte_su2mul(a1, b1, a0, b0, &pA, &pB);       // P = G_{k0+1} * G_{k0}
        if (pr == 0) { MA = pA; MB = pB; }
        else {
            qc nA, nB;
            qte_su2mul(pA, pB, MA, MB, &nA, &nB);   // M = P * M
            MA = nA; MB = nB;
        }
    }

    // Butterfly combine across the wave; higher-d partial multiplies LEFT.
    #pragma unroll
    for (int mask = 1; mask < 64; mask <<= 1) {
        qc sA, sB;
        sA.x = __shfl_xor(MA.x, mask); sA.y = __shfl_xor(MA.y, mask);
        sB.x = __shfl_xor(MB.x, mask); sB.y = __shfl_xor(MB.y, mask);
        const bool lower = (ln & mask) == 0;
        const qc hA = lower ? sA : MA, hB = lower ? sB : MB;  // later (left)
        const qc lA = lower ? MA : sA, lB = lower ? MB : sB;  // earlier (right)
        qte_su2mul(hA, hB, lA, lB, &MA, &MB);
    }

    // v = M . [1,0]^T = (A, -conj(B))
    if (ln == 0) {
        s_v[q][0] = make_float2(MA.x, MA.y);
        s_v[q][1] = make_float2(-MB.x, MB.y);
    }
    __syncthreads();

    // Kronecker product: state[i] = prod_q v[q][bit_q], q=0 most significant.
    // Harness compares the REAL PART only (out_size = B*S*1024 float32).
    for (int i = tid; i < QTE_NSTATE; i += QTE_BLK) {
        float2 a = s_v[0][(i >> (QTE_Q - 1)) & 1];
        qc acc = { a.x, a.y };
        #pragma unroll
        for (int qq = 1; qq < QTE_Q; ++qq) {
            const float2 b = s_v[qq][(i >> (QTE_Q - 1 - qq)) & 1];
            const qc cb = { b.x, b.y };
            qc n;
            n.x = fmaf(acc.x, cb.x, -(acc.y * cb.y));
            n.y = fmaf(acc.x, cb.y,   acc.y * cb.x);
            acc = n;
        }
        const int idx = bs * QTE_NSTATE + i;
        if (idx < out_floats) {
            out[idx] = acc.x;   // real part only
        }
    }
}

extern "C" void kernel_launch(void* const* d_in, const int* in_sizes, int n_in,
                              void* d_out, int out_size, void* d_ws, size_t ws_size,
                              hipStream_t stream) {
    const float* emb = (const float*)d_in[0];  // [B,S,D] float32
    const float* prm = (const float*)d_in[1];  // [D,Q,3] float32
    float* out = (float*)d_out;                // [B,S,1024] float32 (real part)

    const int BS = in_sizes[0] / QTE_D;        // B*S = 512
    qte_kernel<<<BS, QTE_BLK, 0, stream>>>(emb, prm, out, out_size);
}

// Round 6
// 19.428 us; speedup vs baseline: 1.5885x; 1.0919x over previous
//
#include <hip/hip_runtime.h>
#include <math.h>

#define QTE_D      768
#define QTE_Q      10
#define QTE_DPL    12     // gates per lane (768 / 64)
#define QTE_NSTATE 1024   // 2^10
#define QTE_BLK    640    // 10 waves: one wave per qubit chain
#define QTE_TPAD   65     // padded row length for s_tau [12][65]
#define QTE_NGATE  (QTE_Q * QTE_DPL * 64)   // 7680 float4 slots in prmt

struct qc { float x, y; };

// SU(2) matrix is [[A, B], [-conj(B), conj(A)]]; product P*M tracked as (A,B).
__device__ __forceinline__ void qte_su2mul(qc pA, qc pB, qc mA, qc mB,
                                           qc* oA, qc* oB) {
    oA->x = fmaf(pA.x, mA.x, fmaf(-pA.y, mA.y, fmaf(-pB.x, mB.x, -(pB.y * mB.y))));
    oA->y = fmaf(pA.x, mA.y, fmaf( pA.y, mA.x, fmaf( pB.x, mB.y, -(pB.y * mB.x))));
    oB->x = fmaf(pA.x, mB.x, fmaf(-pA.y, mB.y, fmaf( pB.x, mA.x,   pB.y * mA.y)));
    oB->y = fmaf(pA.x, mB.y, fmaf( pA.y, mB.x, fmaf(-pB.x, mA.y,   pB.y * mA.x)));
}

__device__ __forceinline__ float qte_tanh(float x) {
    const float e = __expf(2.0f * x);
    return (e - 1.0f) * __builtin_amdgcn_rcpf(e + 1.0f);
}

// Composite gate Rz@Ry@Rx, angles a_j = tau*p_j; returns (a,b) of SU(2).
__device__ __forceinline__ void qte_gate(float tau, float p0, float p1, float p2,
                                         qc* a, qc* b) {
    const float a0 = tau * p0, a1 = tau * p1, a2 = tau * p2;
    const float s0 = __sinf(a0), c0 = __cosf(a0);
    const float s1 = __sinf(a1), c1 = __cosf(a1);
    const float s2 = __sinf(a2), c2 = __cosf(a2);
    const float u = c1 * c0, v = s1 * s0;
    const float w = s1 * c0, z = c1 * s0;
    a->x =  fmaf(c2, u,   s2 * v);
    a->y =  fmaf(c2, v, -(s2 * u));
    b->x = -fmaf(c2, w,   s2 * z);
    b->y =  fmaf(s2, w, -(c2 * z));
}

// prmt[(q*12 + k)*64 + ln] = float4(prm[d][q][0..2], 0) with d = ln*12 + k
__global__ __launch_bounds__(256)
void qte_transpose(const float* __restrict__ prm, float4* __restrict__ prmt) {
    const int idx = blockIdx.x * 256 + threadIdx.x;
    if (idx < QTE_NGATE) {
        const int ln = idx & 63;
        const int k  = (idx >> 6) % QTE_DPL;
        const int q  = (idx >> 6) / QTE_DPL;
        const int d  = ln * QTE_DPL + k;
        const float* p = prm + (d * QTE_Q + q) * 3;
        prmt[idx] = make_float4(p[0], p[1], p[2], 0.f);
    }
}

template <bool TR>
__global__ __launch_bounds__(QTE_BLK, 5)
void qte_kernel(const float* __restrict__ emb,
                const float* __restrict__ prm,
                const float4* __restrict__ prmt,
                float* __restrict__ out,
                int out_floats) {
    __shared__ float  s_tau[QTE_DPL * QTE_TPAD];  // [k][lane], padded
    __shared__ float2 s_v[QTE_Q][2];

    const int bs  = blockIdx.x;
    const int tid = threadIdx.x;
    const int q   = tid >> 6;   // wave index == qubit index
    const int ln  = tid & 63;

    // Stage tau = (pi/2)*tanh(emb) once per block, transposed to [k][lane].
    for (int d = tid; d < QTE_D; d += QTE_BLK) {
        const float t = 1.57079632679489662f * qte_tanh(emb[bs * QTE_D + d]);
        s_tau[(d % QTE_DPL) * QTE_TPAD + (d / QTE_DPL)] = t;
    }
    __syncthreads();

    // Pair-tree chain: M = P5*...*P0, P_k = G_{2k+1}*G_{2k}; lane owns d=ln*12+k.
    qc MA, MB;
    const float4* gb = TR ? (prmt + q * (QTE_DPL * 64) + ln) : nullptr;
    const float*  pb = TR ? nullptr : (prm + (ln * QTE_DPL * QTE_Q + q) * 3);

    #pragma unroll
    for (int pr = 0; pr < QTE_DPL / 2; ++pr) {
        const int k0 = 2 * pr;
        const float tau0 = s_tau[k0 * QTE_TPAD + ln];
        const float tau1 = s_tau[(k0 + 1) * QTE_TPAD + ln];
        qc a0, b0, a1, b1;
        if (TR) {
            const float4 g0 = gb[k0 * 64];
            const float4 g1 = gb[(k0 + 1) * 64];
            qte_gate(tau0, g0.x, g0.y, g0.z, &a0, &b0);
            qte_gate(tau1, g1.x, g1.y, g1.z, &a1, &b1);
        } else {
            const float* P0 = pb + k0 * (QTE_Q * 3);
            const float* P1 = P0 + QTE_Q * 3;
            qte_gate(tau0, P0[0], P0[1], P0[2], &a0, &b0);
            qte_gate(tau1, P1[0], P1[1], P1[2], &a1, &b1);
        }
        qc pA, pB;
        qte_su2mul(a1, b1, a0, b0, &pA, &pB);       // P = G_{k0+1} * G_{k0}
        if (pr == 0) { MA = pA; MB = pB; }
        else {
            qc nA, nB;
            qte_su2mul(pA, pB, MA, MB, &nA, &nB);   // M = P * M
            MA = nA; MB = nB;
        }
    }

    // Butterfly combine across the wave; higher-d partial multiplies LEFT.
    #pragma unroll
    for (int mask = 1; mask < 64; mask <<= 1) {
        qc sA, sB;
        sA.x = __shfl_xor(MA.x, mask); sA.y = __shfl_xor(MA.y, mask);
        sB.x = __shfl_xor(MB.x, mask); sB.y = __shfl_xor(MB.y, mask);
        const bool lower = (ln & mask) == 0;
        const qc hA = lower ? sA : MA, hB = lower ? sB : MB;  // later (left)
        const qc lA = lower ? MA : sA, lB = lower ? MB : sB;  // earlier (right)
        qte_su2mul(hA, hB, lA, lB, &MA, &MB);
    }

    // v = M . [1,0]^T = (A, -conj(B))
    if (ln == 0) {
        s_v[q][0] = make_float2(MA.x, MA.y);
        s_v[q][1] = make_float2(-MB.x, MB.y);
    }
    __syncthreads();

    // Kronecker product: state[i] = prod_q v[q][bit_q], q=0 most significant.
    // Harness compares the REAL PART only (out_size = B*S*1024 float32).
    for (int i = tid; i < QTE_NSTATE; i += QTE_BLK) {
        float2 a = s_v[0][(i >> (QTE_Q - 1)) & 1];
        qc acc = { a.x, a.y };
        #pragma unroll
        for (int qq = 1; qq < QTE_Q; ++qq) {
            const float2 b = s_v[qq][(i >> (QTE_Q - 1 - qq)) & 1];
            qc n;
            n.x = fmaf(acc.x, b.x, -(acc.y * b.y));
            n.y = fmaf(acc.x, b.y,   acc.y * b.x);
            acc = n;
        }
        const int idx = bs * QTE_NSTATE + i;
        if (idx < out_floats) {
            out[idx] = acc.x;   // real part only
        }
    }
}

extern "C" void kernel_launch(void* const* d_in, const int* in_sizes, int n_in,
                              void* d_out, int out_size, void* d_ws, size_t ws_size,
                              hipStream_t stream) {
    const float* emb = (const float*)d_in[0];  // [B,S,D] float32
    const float* prm = (const float*)d_in[1];  // [D,Q,3] float32
    float* out = (float*)d_out;                // [B,S,1024] float32 (real part)

    const int BS = in_sizes[0] / QTE_D;        // B*S = 512

    if (ws_size >= QTE_NGATE * sizeof(float4)) {
        float4* prmt = (float4*)d_ws;
        qte_transpose<<<(QTE_NGATE + 255) / 256, 256, 0, stream>>>(prm, prmt);
        qte_kernel<true><<<BS, QTE_BLK, 0, stream>>>(emb, prm, prmt, out, out_size);
    } else {
        qte_kernel<false><<<BS, QTE_BLK, 0, stream>>>(emb, prm, nullptr, out, out_size);
    }
}

// Round 7
// 19.269 us; speedup vs baseline: 1.6016x; 1.0082x over previous
//
#include <hip/hip_runtime.h>
#include <math.h>

#define QTE_D      768
#define QTE_Q      10
#define QTE_DPL    12     // gates per lane (768 / 64)
#define QTE_BLK    640    // 10 waves: one wave per qubit chain
#define QTE_TPAD   65     // padded row length for s_tau [12][65]
#define QTE_NGATE  (QTE_Q * QTE_DPL * 64)   // 7680 float4 slots in prmt

struct qc { float x, y; };

// SU(2) matrix [[A, B], [-conj(B), conj(A)]]; product P*M tracked as (A,B).
__device__ __forceinline__ void qte_su2mul(qc pA, qc pB, qc mA, qc mB,
                                           qc* oA, qc* oB) {
    oA->x = fmaf(pA.x, mA.x, fmaf(-pA.y, mA.y, fmaf(-pB.x, mB.x, -(pB.y * mB.y))));
    oA->y = fmaf(pA.x, mA.y, fmaf( pA.y, mA.x, fmaf( pB.x, mB.y, -(pB.y * mB.x))));
    oB->x = fmaf(pA.x, mB.x, fmaf(-pA.y, mB.y, fmaf( pB.x, mA.x,   pB.y * mA.y)));
    oB->y = fmaf(pA.x, mB.y, fmaf( pA.y, mB.x, fmaf(-pB.x, mA.y,   pB.y * mA.x)));
}

__device__ __forceinline__ qc qte_cmul(qc a, qc b) {
    qc r;
    r.x = fmaf(a.x, b.x, -(a.y * b.y));
    r.y = fmaf(a.x, b.y,   a.y * b.x);
    return r;
}

__device__ __forceinline__ float qte_tanh(float x) {
    const float e = __expf(2.0f * x);
    return (e - 1.0f) * __builtin_amdgcn_rcpf(e + 1.0f);
}

// Composite gate Rz@Ry@Rx, angles a_j = tau*p_j; returns (a,b) of SU(2).
__device__ __forceinline__ void qte_gate(float tau, float p0, float p1, float p2,
                                         qc* a, qc* b) {
    const float a0 = tau * p0, a1 = tau * p1, a2 = tau * p2;
    const float s0 = __sinf(a0), c0 = __cosf(a0);
    const float s1 = __sinf(a1), c1 = __cosf(a1);
    const float s2 = __sinf(a2), c2 = __cosf(a2);
    const float u = c1 * c0, v = s1 * s0;
    const float w = s1 * c0, z = c1 * s0;
    a->x =  fmaf(c2, u,   s2 * v);
    a->y =  fmaf(c2, v, -(s2 * u));
    b->x = -fmaf(c2, w,   s2 * z);
    b->y =  fmaf(s2, w, -(c2 * z));
}

// prmt[(q*12 + k)*64 + ln] = float4(prm[d][q][0..2], 0) with d = ln*12 + k
__global__ __launch_bounds__(128)
void qte_transpose(const float* __restrict__ prm, float4* __restrict__ prmt) {
    const int idx = blockIdx.x * 128 + threadIdx.x;
    if (idx < QTE_NGATE) {
        const int ln = idx & 63;
        const int k  = (idx >> 6) % QTE_DPL;
        const int q  = (idx >> 6) / QTE_DPL;
        const int d  = ln * QTE_DPL + k;
        const float* p = prm + (d * QTE_Q + q) * 3;
        prmt[idx] = make_float4(p[0], p[1], p[2], 0.f);
    }
}

template <bool TR>
__device__ __forceinline__ void qte_loadgate(const float4* gb, const float* pb,
                                             const float* s_tau, int ln, int k,
                                             qc* a, qc* b) {
    const float tau = s_tau[k * QTE_TPAD + ln];
    if (TR) {
        const float4 g = gb[k * 64];
        qte_gate(tau, g.x, g.y, g.z, a, b);
    } else {
        const float* p = pb + k * (QTE_Q * 3);
        qte_gate(tau, p[0], p[1], p[2], a, b);
    }
}

template <bool TR>
__global__ __launch_bounds__(QTE_BLK, 5)
void qte_kernel(const float* __restrict__ emb,
                const float* __restrict__ prm,
                const float4* __restrict__ prmt,
                float* __restrict__ out,
                int out_floats) {
    __shared__ float  s_tau[QTE_DPL * QTE_TPAD];  // [k][lane], padded
    __shared__ float2 s_v[QTE_Q][2];
    __shared__ float2 s_pre[32];
    __shared__ float2 s_suf[32];

    const int bs  = blockIdx.x;
    const int tid = threadIdx.x;
    const int q   = tid >> 6;   // wave index == qubit index
    const int ln  = tid & 63;

    // Stage tau = (pi/2)*tanh(emb) once per block, transposed to [k][lane].
    for (int d = tid; d < QTE_D; d += QTE_BLK) {
        const float t = 1.57079632679489662f * qte_tanh(emb[bs * QTE_D + d]);
        s_tau[(d % QTE_DPL) * QTE_TPAD + (d / QTE_DPL)] = t;
    }
    __syncthreads();

    const float4* gb = TR ? (prmt + q * (QTE_DPL * 64) + ln) : nullptr;
    const float*  pb = TR ? nullptr : (prm + (ln * QTE_DPL * QTE_Q + q) * 3);

    // Binary-tree chain: M = G11*G10*...*G0 (later d multiplies LEFT), depth 4.
    qc a0, b0, a1, b1, pA0, pB0, pA1, pB1;
    qc qA0, qB0, qA1, qB1, rA, rB, MA, MB;

    // Q0 = (G3*G2)*(G1*G0)
    qte_loadgate<TR>(gb, pb, s_tau, ln, 0, &a0, &b0);
    qte_loadgate<TR>(gb, pb, s_tau, ln, 1, &a1, &b1);
    qte_su2mul(a1, b1, a0, b0, &pA0, &pB0);
    qte_loadgate<TR>(gb, pb, s_tau, ln, 2, &a0, &b0);
    qte_loadgate<TR>(gb, pb, s_tau, ln, 3, &a1, &b1);
    qte_su2mul(a1, b1, a0, b0, &pA1, &pB1);
    qte_su2mul(pA1, pB1, pA0, pB0, &qA0, &qB0);
    // Q1 = (G7*G6)*(G5*G4)
    qte_loadgate<TR>(gb, pb, s_tau, ln, 4, &a0, &b0);
    qte_loadgate<TR>(gb, pb, s_tau, ln, 5, &a1, &b1);
    qte_su2mul(a1, b1, a0, b0, &pA0, &pB0);
    qte_loadgate<TR>(gb, pb, s_tau, ln, 6, &a0, &b0);
    qte_loadgate<TR>(gb, pb, s_tau, ln, 7, &a1, &b1);
    qte_su2mul(a1, b1, a0, b0, &pA1, &pB1);
    qte_su2mul(pA1, pB1, pA0, pB0, &qA1, &qB1);
    // R = Q1*Q0
    qte_su2mul(qA1, qB1, qA0, qB0, &rA, &rB);
    // Q2 = (G11*G10)*(G9*G8)
    qte_loadgate<TR>(gb, pb, s_tau, ln, 8, &a0, &b0);
    qte_loadgate<TR>(gb, pb, s_tau, ln, 9, &a1, &b1);
    qte_su2mul(a1, b1, a0, b0, &pA0, &pB0);
    qte_loadgate<TR>(gb, pb, s_tau, ln, 10, &a0, &b0);
    qte_loadgate<TR>(gb, pb, s_tau, ln, 11, &a1, &b1);
    qte_su2mul(a1, b1, a0, b0, &pA1, &pB1);
    qte_su2mul(pA1, pB1, pA0, pB0, &qA0, &qB0);
    // M = Q2*R
    qte_su2mul(qA0, qB0, rA, rB, &MA, &MB);

    // Butterfly combine across the wave; higher-d partial multiplies LEFT.
    #pragma unroll
    for (int mask = 1; mask < 64; mask <<= 1) {
        qc sA, sB;
        sA.x = __shfl_xor(MA.x, mask); sA.y = __shfl_xor(MA.y, mask);
        sB.x = __shfl_xor(MB.x, mask); sB.y = __shfl_xor(MB.y, mask);
        const bool lower = (ln & mask) == 0;
        const qc hA = lower ? sA : MA, hB = lower ? sB : MB;  // later (left)
        const qc lA = lower ? MA : sA, lB = lower ? MB : sB;  // earlier (right)
        qte_su2mul(hA, hB, lA, lB, &MA, &MB);
    }

    // v = M . [1,0]^T = (A, -conj(B))
    if (ln == 0) {
        s_v[q][0] = make_float2(MA.x, MA.y);
        s_v[q][1] = make_float2(-MB.x, MB.y);
    }
    __syncthreads();

    // Prefix (q0..q4) and suffix (q5..q9) products: 32 each, by threads 0..63.
    if (tid < 64) {
        const int lo = tid & 31;
        const int qb = (tid < 32) ? 0 : 5;
        qc f[5];
        #pragma unroll
        for (int j = 0; j < 5; ++j) {
            const float2 v = s_v[qb + j][(lo >> (4 - j)) & 1];
            f[j].x = v.x; f[j].y = v.y;
        }
        const qc m01 = qte_cmul(f[0], f[1]);
        const qc m23 = qte_cmul(f[2], f[3]);
        const qc m03 = qte_cmul(m01, m23);
        const qc res = qte_cmul(m03, f[4]);
        if (tid < 32) s_pre[lo] = make_float2(res.x, res.y);
        else          s_suf[lo] = make_float2(res.x, res.y);
    }
    __syncthreads();

    // state[i] = pre[i>>5] * suf[i&31]; harness compares REAL part only.
    // Thread t stores real(state[2t]), real(state[2t+1]) as one float2.
    if (tid < 512) {
        const float2 pre = s_pre[tid >> 4];
        const float2 sa  = s_suf[(2 * tid) & 31];
        const float2 sb  = s_suf[((2 * tid) & 31) + 1];
        float2 o;
        o.x = fmaf(pre.x, sa.x, -(pre.y * sa.y));
        o.y = fmaf(pre.x, sb.x, -(pre.y * sb.y));
        const int idx = (bs << 9) + tid;
        if (2 * idx + 1 < out_floats) {
            reinterpret_cast<float2*>(out)[idx] = o;
        }
    }
}

extern "C" void kernel_launch(void* const* d_in, const int* in_sizes, int n_in,
                              void* d_out, int out_size, void* d_ws, size_t ws_size,
                              hipStream_t stream) {
    const float* emb = (const float*)d_in[0];  // [B,S,D] float32
    const float* prm = (const float*)d_in[1];  // [D,Q,3] float32
    float* out = (float*)d_out;                // [B,S,1024] float32 (real part)

    const int BS = in_sizes[0] / QTE_D;        // B*S = 512

    if (ws_size >= QTE_NGATE * sizeof(float4)) {
        float4* prmt = (float4*)d_ws;
        qte_transpose<<<(QTE_NGATE + 127) / 128, 128, 0, stream>>>(prm, prmt);
        qte_kernel<true><<<BS, QTE_BLK, 0, stream>>>(emb, prm, prmt, out, out_size);
    } else {
        qte_kernel<false><<<BS, QTE_BLK, 0, stream>>>(emb, prm, nullptr, out, out_size);
    }
}

// Round 8
// 18.773 us; speedup vs baseline: 1.6439x; 1.0264x over previous
//
#include <hip/hip_runtime.h>
#include <math.h>

#define QTE_D      768
#define QTE_Q      10
#define QTE_DPL    12     // gates per lane (768 / 64)
#define QTE_BLK    640    // 10 waves: one wave per qubit chain
#define QTE_TPAD   65     // padded row length for s_tau [12][65]
#define QTE_NGATE  (QTE_Q * QTE_DPL * 64)   // 7680 float4 slots in prmt
#define QTE_PRMN   (QTE_D * QTE_Q * 3)      // 23040 dwords in prm

struct qc { float x, y; };

// SU(2) matrix [[A, B], [-conj(B), conj(A)]]; product P*M tracked as (A,B).
__device__ __forceinline__ void qte_su2mul(qc pA, qc pB, qc mA, qc mB,
                                           qc* oA, qc* oB) {
    oA->x = fmaf(pA.x, mA.x, fmaf(-pA.y, mA.y, fmaf(-pB.x, mB.x, -(pB.y * mB.y))));
    oA->y = fmaf(pA.x, mA.y, fmaf( pA.y, mA.x, fmaf( pB.x, mB.y, -(pB.y * mB.x))));
    oB->x = fmaf(pA.x, mB.x, fmaf(-pA.y, mB.y, fmaf( pB.x, mA.x,   pB.y * mA.y)));
    oB->y = fmaf(pA.x, mB.y, fmaf( pA.y, mB.x, fmaf(-pB.x, mA.y,   pB.y * mA.x)));
}

__device__ __forceinline__ qc qte_cmul(qc a, qc b) {
    qc r;
    r.x = fmaf(a.x, b.x, -(a.y * b.y));
    r.y = fmaf(a.x, b.y,   a.y * b.x);
    return r;
}

__device__ __forceinline__ float qte_tanh(float x) {
    const float e = __expf(2.0f * x);
    return (e - 1.0f) * __builtin_amdgcn_rcpf(e + 1.0f);
}

// Composite gate Rz@Ry@Rx, angles a_j = tau*p_j; returns (a,b) of SU(2).
__device__ __forceinline__ void qte_gate(float tau, float p0, float p1, float p2,
                                         qc* a, qc* b) {
    const float a0 = tau * p0, a1 = tau * p1, a2 = tau * p2;
    const float s0 = __sinf(a0), c0 = __cosf(a0);
    const float s1 = __sinf(a1), c1 = __cosf(a1);
    const float s2 = __sinf(a2), c2 = __cosf(a2);
    const float u = c1 * c0, v = s1 * s0;
    const float w = s1 * c0, z = c1 * s0;
    a->x =  fmaf(c2, u,   s2 * v);
    a->y =  fmaf(c2, v, -(s2 * u));
    b->x = -fmaf(c2, w,   s2 * z);
    b->y =  fmaf(s2, w, -(c2 * z));
}

// Coalesced-read / scattered-write transpose:
// prm dword i = prm[d][q][j]  (j = i%3, q = (i/3)%10, d = i/30)
// -> prmt float4 slot (q*12 + k)*64 + ln, component j, with ln = d/12, k = d%12.
__global__ __launch_bounds__(256)
void qte_transpose(const float* __restrict__ prm, float* __restrict__ prmt4) {
    const int i = blockIdx.x * 256 + threadIdx.x;
    if (i < QTE_PRMN) {
        const float v = prm[i];
        const int j = i % 3;
        const int q = (i / 3) % QTE_Q;
        const int d = i / (3 * QTE_Q);
        const int ln = d / QTE_DPL;
        const int k  = d % QTE_DPL;
        prmt4[(((q * QTE_DPL + k) * 64) + ln) * 4 + j] = v;
    }
}

template <bool TR>
__device__ __forceinline__ void qte_loadgate(const float4* gb, const float* pb,
                                             const float* s_tau, int ln, int k,
                                             qc* a, qc* b) {
    const float tau = s_tau[k * QTE_TPAD + ln];
    if (TR) {
        const float4 g = gb[k * 64];
        qte_gate(tau, g.x, g.y, g.z, a, b);
    } else {
        const float* p = pb + k * (QTE_Q * 3);
        qte_gate(tau, p[0], p[1], p[2], a, b);
    }
}

template <bool TR>
__global__ __launch_bounds__(QTE_BLK, 5)
void qte_kernel(const float* __restrict__ emb,
                const float* __restrict__ prm,
                const float4* __restrict__ prmt,
                float* __restrict__ out,
                int out_floats) {
    __shared__ float  s_tau[QTE_DPL * QTE_TPAD];  // [k][lane], padded
    __shared__ float2 s_v[QTE_Q][2];
    __shared__ float2 s_pre[32];
    __shared__ float2 s_suf[32];

    const int bs  = blockIdx.x;
    const int tid = threadIdx.x;
    const int q   = tid >> 6;   // wave index == qubit index
    const int ln  = tid & 63;

    // Stage tau = (pi/2)*tanh(emb) once per block, transposed to [k][lane].
    for (int d = tid; d < QTE_D; d += QTE_BLK) {
        const float t = 1.57079632679489662f * qte_tanh(emb[bs * QTE_D + d]);
        s_tau[(d % QTE_DPL) * QTE_TPAD + (d / QTE_DPL)] = t;
    }
    __syncthreads();

    const float4* gb = TR ? (prmt + q * (QTE_DPL * 64) + ln) : nullptr;
    const float*  pb = TR ? nullptr : (prm + (ln * QTE_DPL * QTE_Q + q) * 3);

    // Binary-tree chain: M = G11*G10*...*G0 (later d multiplies LEFT), depth 4.
    qc a0, b0, a1, b1, pA0, pB0, pA1, pB1;
    qc qA0, qB0, qA1, qB1, rA, rB, MA, MB;

    // Q0 = (G3*G2)*(G1*G0)
    qte_loadgate<TR>(gb, pb, s_tau, ln, 0, &a0, &b0);
    qte_loadgate<TR>(gb, pb, s_tau, ln, 1, &a1, &b1);
    qte_su2mul(a1, b1, a0, b0, &pA0, &pB0);
    qte_loadgate<TR>(gb, pb, s_tau, ln, 2, &a0, &b0);
    qte_loadgate<TR>(gb, pb, s_tau, ln, 3, &a1, &b1);
    qte_su2mul(a1, b1, a0, b0, &pA1, &pB1);
    qte_su2mul(pA1, pB1, pA0, pB0, &qA0, &qB0);
    // Q1 = (G7*G6)*(G5*G4)
    qte_loadgate<TR>(gb, pb, s_tau, ln, 4, &a0, &b0);
    qte_loadgate<TR>(gb, pb, s_tau, ln, 5, &a1, &b1);
    qte_su2mul(a1, b1, a0, b0, &pA0, &pB0);
    qte_loadgate<TR>(gb, pb, s_tau, ln, 6, &a0, &b0);
    qte_loadgate<TR>(gb, pb, s_tau, ln, 7, &a1, &b1);
    qte_su2mul(a1, b1, a0, b0, &pA1, &pB1);
    qte_su2mul(pA1, pB1, pA0, pB0, &qA1, &qB1);
    // R = Q1*Q0
    qte_su2mul(qA1, qB1, qA0, qB0, &rA, &rB);
    // Q2 = (G11*G10)*(G9*G8)
    qte_loadgate<TR>(gb, pb, s_tau, ln, 8, &a0, &b0);
    qte_loadgate<TR>(gb, pb, s_tau, ln, 9, &a1, &b1);
    qte_su2mul(a1, b1, a0, b0, &pA0, &pB0);
    qte_loadgate<TR>(gb, pb, s_tau, ln, 10, &a0, &b0);
    qte_loadgate<TR>(gb, pb, s_tau, ln, 11, &a1, &b1);
    qte_su2mul(a1, b1, a0, b0, &pA1, &pB1);
    qte_su2mul(pA1, pB1, pA0, pB0, &qA0, &qB0);
    // M = Q2*R
    qte_su2mul(qA0, qB0, rA, rB, &MA, &MB);

    // Butterfly combine across the wave; higher-d partial multiplies LEFT.
    #pragma unroll
    for (int mask = 1; mask < 64; mask <<= 1) {
        qc sA, sB;
        sA.x = __shfl_xor(MA.x, mask); sA.y = __shfl_xor(MA.y, mask);
        sB.x = __shfl_xor(MB.x, mask); sB.y = __shfl_xor(MB.y, mask);
        const bool lower = (ln & mask) == 0;
        const qc hA = lower ? sA : MA, hB = lower ? sB : MB;  // later (left)
        const qc lA = lower ? MA : sA, lB = lower ? MB : sB;  // earlier (right)
        qte_su2mul(hA, hB, lA, lB, &MA, &MB);
    }

    // v = M . [1,0]^T = (A, -conj(B))
    if (ln == 0) {
        s_v[q][0] = make_float2(MA.x, MA.y);
        s_v[q][1] = make_float2(-MB.x, MB.y);
    }
    __syncthreads();

    // Prefix (q0..q4) and suffix (q5..q9) products: 32 each, by threads 0..63.
    if (tid < 64) {
        const int lo = tid & 31;
        const int qb = (tid < 32) ? 0 : 5;
        qc f[5];
        #pragma unroll
        for (int j = 0; j < 5; ++j) {
            const float2 v = s_v[qb + j][(lo >> (4 - j)) & 1];
            f[j].x = v.x; f[j].y = v.y;
        }
        const qc m01 = qte_cmul(f[0], f[1]);
        const qc m23 = qte_cmul(f[2], f[3]);
        const qc m03 = qte_cmul(m01, m23);
        const qc res = qte_cmul(m03, f[4]);
        if (tid < 32) s_pre[lo] = make_float2(res.x, res.y);
        else          s_suf[lo] = make_float2(res.x, res.y);
    }
    __syncthreads();

    // state[i] = pre[i>>5] * suf[i&31]; harness compares REAL part only.
    // Thread t stores real(state[2t]), real(state[2t+1]) as one float2.
    if (tid < 512) {
        const float2 pre = s_pre[tid >> 4];
        const float2 sa  = s_suf[(2 * tid) & 31];
        const float2 sb  = s_suf[((2 * tid) & 31) + 1];
        float2 o;
        o.x = fmaf(pre.x, sa.x, -(pre.y * sa.y));
        o.y = fmaf(pre.x, sb.x, -(pre.y * sb.y));
        const int idx = (bs << 9) + tid;
        if (2 * idx + 1 < out_floats) {
            reinterpret_cast<float2*>(out)[idx] = o;
        }
    }
}

extern "C" void kernel_launch(void* const* d_in, const int* in_sizes, int n_in,
                              void* d_out, int out_size, void* d_ws, size_t ws_size,
                              hipStream_t stream) {
    const float* emb = (const float*)d_in[0];  // [B,S,D] float32
    const float* prm = (const float*)d_in[1];  // [D,Q,3] float32
    float* out = (float*)d_out;                // [B,S,1024] float32 (real part)

    const int BS = in_sizes[0] / QTE_D;        // B*S = 512

    if (ws_size >= QTE_NGATE * sizeof(float4)) {
        float4* prmt = (float4*)d_ws;
        qte_transpose<<<(QTE_PRMN + 255) / 256, 256, 0, stream>>>(prm, (float*)prmt);
        qte_kernel<true><<<BS, QTE_BLK, 0, stream>>>(emb, prm, prmt, out, out_size);
    } else {
        qte_kernel<false><<<BS, QTE_BLK, 0, stream>>>(emb, prm, nullptr, out, out_size);
    }
}

// Round 9
// 14.352 us; speedup vs baseline: 2.1504x; 1.3081x over previous
//
#include <hip/hip_runtime.h>
#include <math.h>

#define QTE_D      768
#define QTE_Q      10
#define QTE_DPL    12     // gates per chain-segment (768 / 64)
#define QTE_BLK    640    // 64 segments x 10 qubits, q-major: tid = c*10 + q

typedef float qte_f4 __attribute__((ext_vector_type(4), aligned(4)));

struct qc { float x, y; };

// SU(2) matrix [[A, B], [-conj(B), conj(A)]]; product P*M tracked as (A,B).
__device__ __forceinline__ void qte_su2mul(qc pA, qc pB, qc mA, qc mB,
                                           qc* oA, qc* oB) {
    oA->x = fmaf(pA.x, mA.x, fmaf(-pA.y, mA.y, fmaf(-pB.x, mB.x, -(pB.y * mB.y))));
    oA->y = fmaf(pA.x, mA.y, fmaf( pA.y, mA.x, fmaf( pB.x, mB.y, -(pB.y * mB.x))));
    oB->x = fmaf(pA.x, mB.x, fmaf(-pA.y, mB.y, fmaf( pB.x, mA.x,   pB.y * mA.y)));
    oB->y = fmaf(pA.x, mB.y, fmaf( pA.y, mB.x, fmaf(-pB.x, mA.y,   pB.y * mA.x)));
}

__device__ __forceinline__ qc qte_cmul(qc a, qc b) {
    qc r;
    r.x = fmaf(a.x, b.x, -(a.y * b.y));
    r.y = fmaf(a.x, b.y,   a.y * b.x);
    return r;
}

__device__ __forceinline__ float qte_tanh(float x) {
    const float e = __expf(2.0f * x);
    return (e - 1.0f) * __builtin_amdgcn_rcpf(e + 1.0f);
}

// Composite gate Rz@Ry@Rx, angles a_j = tau*p_j; returns (a,b) of SU(2).
__device__ __forceinline__ void qte_gate(float tau, float p0, float p1, float p2,
                                         qc* a, qc* b) {
    const float a0 = tau * p0, a1 = tau * p1, a2 = tau * p2;
    const float s0 = __sinf(a0), c0 = __cosf(a0);
    const float s1 = __sinf(a1), c1 = __cosf(a1);
    const float s2 = __sinf(a2), c2 = __cosf(a2);
    const float u = c1 * c0, v = s1 * s0;
    const float w = s1 * c0, z = c1 * s0;
    a->x =  fmaf(c2, u,   s2 * v);
    a->y =  fmaf(c2, v, -(s2 * u));
    b->x = -fmaf(c2, w,   s2 * z);
    b->y =  fmaf(s2, w, -(c2 * z));
}

// Fetch gate k (compile-time constant at call sites) for this thread's (q, c).
// gp = prm + c*12*30 + q*3; gate dwords at gp + k*30 .. +2.
// k=11 would read one dword past prm's end with a float4, so shift by -1.
__device__ __forceinline__ void qte_fetch_gate(const float* __restrict__ gp,
                                               const float* __restrict__ tb,
                                               int k, qc* a, qc* b) {
    const float tau = tb[k];
    if (k < 11) {
        const qte_f4 g = *reinterpret_cast<const qte_f4*>(gp + k * 30);
        qte_gate(tau, g.x, g.y, g.z, a, b);
    } else {
        const qte_f4 g = *reinterpret_cast<const qte_f4*>(gp + k * 30 - 1);
        qte_gate(tau, g.y, g.z, g.w, a, b);
    }
}

__global__ __launch_bounds__(QTE_BLK, 5)
void qte_kernel(const float* __restrict__ emb,
                const float* __restrict__ prm,
                float* __restrict__ out,
                int out_floats) {
    __shared__ float  s_tau[QTE_D];
    __shared__ float4 s_pa[64][QTE_Q];   // (A.x, A.y, B.x, B.y)
    __shared__ float4 s_pb[32][QTE_Q];
    __shared__ float2 s_v[QTE_Q][2];
    __shared__ float2 s_pre[32];
    __shared__ float2 s_suf[32];

    const int bs  = blockIdx.x;
    const int tid = threadIdx.x;
    const int c   = tid / QTE_Q;        // chain segment 0..63
    const int q   = tid - c * QTE_Q;    // qubit 0..9

    // Stage tau = (pi/2)*tanh(emb), coalesced.
    for (int d = tid; d < QTE_D; d += QTE_BLK) {
        s_tau[d] = 1.57079632679489662f * qte_tanh(emb[bs * QTE_D + d]);
    }
    __syncthreads();

    const float* tb = s_tau + c * QTE_DPL;
    const float* gp = prm + (c * QTE_DPL * QTE_Q + q) * 3;

    // Binary-tree product of this segment's 12 gates (later d multiplies LEFT).
    qc a0, b0, a1, b1, pA0, pB0, pA1, pB1;
    qc qA0, qB0, qA1, qB1, rA, rB, MA, MB;

    // Q0 = (G3*G2)*(G1*G0)
    qte_fetch_gate(gp, tb, 0, &a0, &b0);
    qte_fetch_gate(gp, tb, 1, &a1, &b1);
    qte_su2mul(a1, b1, a0, b0, &pA0, &pB0);
    qte_fetch_gate(gp, tb, 2, &a0, &b0);
    qte_fetch_gate(gp, tb, 3, &a1, &b1);
    qte_su2mul(a1, b1, a0, b0, &pA1, &pB1);
    qte_su2mul(pA1, pB1, pA0, pB0, &qA0, &qB0);
    // Q1 = (G7*G6)*(G5*G4)
    qte_fetch_gate(gp, tb, 4, &a0, &b0);
    qte_fetch_gate(gp, tb, 5, &a1, &b1);
    qte_su2mul(a1, b1, a0, b0, &pA0, &pB0);
    qte_fetch_gate(gp, tb, 6, &a0, &b0);
    qte_fetch_gate(gp, tb, 7, &a1, &b1);
    qte_su2mul(a1, b1, a0, b0, &pA1, &pB1);
    qte_su2mul(pA1, pB1, pA0, pB0, &qA1, &qB1);
    // R = Q1*Q0
    qte_su2mul(qA1, qB1, qA0, qB0, &rA, &rB);
    // Q2 = (G11*G10)*(G9*G8)
    qte_fetch_gate(gp, tb, 8, &a0, &b0);
    qte_fetch_gate(gp, tb, 9, &a1, &b1);
    qte_su2mul(a1, b1, a0, b0, &pA0, &pB0);
    qte_fetch_gate(gp, tb, 10, &a0, &b0);
    qte_fetch_gate(gp, tb, 11, &a1, &b1);
    qte_su2mul(a1, b1, a0, b0, &pA1, &pB1);
    qte_su2mul(pA1, pB1, pA0, pB0, &qA0, &qB0);
    // M = Q2*R  (covers this segment's 12 gates, in order)
    qte_su2mul(qA0, qB0, rA, rB, &MA, &MB);

    s_pa[c][q] = make_float4(MA.x, MA.y, MB.x, MB.y);
    __syncthreads();

    // LDS pairwise-fold tree: adjacent segments, higher-c operand on the LEFT.
    // 64 -> 32 -> 16 -> 8 -> 4 -> 2 -> 1, ping-pong pa <-> pb.
#define QTE_ROUND(SRC, DST, HALF)                                          \
    if (tid < QTE_Q * (HALF)) {                                            \
        const int j  = tid / QTE_Q;                                        \
        const int qq = tid - j * QTE_Q;                                    \
        const float4 lo = SRC[2 * j][qq];                                  \
        const float4 hi = SRC[2 * j + 1][qq];                              \
        const qc lA = {lo.x, lo.y}, lB = {lo.z, lo.w};                     \
        const qc hA = {hi.x, hi.y}, hB = {hi.z, hi.w};                     \
        qc oA, oB;                                                         \
        qte_su2mul(hA, hB, lA, lB, &oA, &oB);                              \
        DST[j][qq] = make_float4(oA.x, oA.y, oB.x, oB.y);                  \
    }                                                                      \
    __syncthreads();

    QTE_ROUND(s_pa, s_pb, 32)
    QTE_ROUND(s_pb, s_pa, 16)
    QTE_ROUND(s_pa, s_pb, 8)
    QTE_ROUND(s_pb, s_pa, 4)
    QTE_ROUND(s_pa, s_pb, 2)
#undef QTE_ROUND

    // Final round (HALF=1): write v = M.[1,0]^T = (A, -conj(B)) directly.
    if (tid < QTE_Q) {
        const float4 lo = s_pb[0][tid];
        const float4 hi = s_pb[1][tid];
        const qc lA = {lo.x, lo.y}, lB = {lo.z, lo.w};
        const qc hA = {hi.x, hi.y}, hB = {hi.z, hi.w};
        qc oA, oB;
        qte_su2mul(hA, hB, lA, lB, &oA, &oB);
        s_v[tid][0] = make_float2(oA.x, oA.y);
        s_v[tid][1] = make_float2(-oB.x, oB.y);
    }
    __syncthreads();

    // Prefix (q0..q4) and suffix (q5..q9) products: 32 each.
    if (tid < 64) {
        const int lo = tid & 31;
        const int qb = (tid < 32) ? 0 : 5;
        qc f[5];
        #pragma unroll
        for (int j = 0; j < 5; ++j) {
            const float2 v = s_v[qb + j][(lo >> (4 - j)) & 1];
            f[j].x = v.x; f[j].y = v.y;
        }
        const qc m01 = qte_cmul(f[0], f[1]);
        const qc m23 = qte_cmul(f[2], f[3]);
        const qc m03 = qte_cmul(m01, m23);
        const qc res = qte_cmul(m03, f[4]);
        if (tid < 32) s_pre[lo] = make_float2(res.x, res.y);
        else          s_suf[lo] = make_float2(res.x, res.y);
    }
    __syncthreads();

    // state[i] = pre[i>>5] * suf[i&31]; harness compares REAL part only.
    // Thread t stores real(state[2t]), real(state[2t+1]) as one float2.
    if (tid < 512) {
        const float2 pre = s_pre[tid >> 4];
        const float2 sa  = s_suf[(2 * tid) & 31];
        const float2 sb  = s_suf[((2 * tid) & 31) + 1];
        float2 o;
        o.x = fmaf(pre.x, sa.x, -(pre.y * sa.y));
        o.y = fmaf(pre.x, sb.x, -(pre.y * sb.y));
        const int idx = (bs << 9) + tid;
        if (2 * idx + 1 < out_floats) {
            reinterpret_cast<float2*>(out)[idx] = o;
        }
    }
}

extern "C" void kernel_launch(void* const* d_in, const int* in_sizes, int n_in,
                              void* d_out, int out_size, void* d_ws, size_t ws_size,
                              hipStream_t stream) {
    const float* emb = (const float*)d_in[0];  // [B,S,D] float32
    const float* prm = (const float*)d_in[1];  // [D,Q,3] float32
    float* out = (float*)d_out;                // [B,S,1024] float32 (real part)
    (void)d_ws; (void)ws_size; (void)n_in;

    const int BS = in_sizes[0] / QTE_D;        // B*S = 512
    qte_kernel<<<BS, QTE_BLK, 0, stream>>>(emb, prm, out, out_size);
}